// Round 1
// 103.602 us; speedup vs baseline: 1.0306x; 1.0306x over previous
//
#include <hip/hip_runtime.h>
#include <hip/hip_fp16.h>

#define VOC      512
#define EMB      128
#define L_SEQ    32
#define NWORDS   16384
#define NCOL     416
#define WPB      128     // words per conv block
#define SCP      48      // sc row pitch in u16 (96 B, 16B-aligned, <=2-way banks)

// Half-split subtables: sub = seg*2 + half (8 filters each).
// Widths in halves: seg0:16, seg1/2:32, seg3/4:64. Row VOC (512) is all-zero.
__device__ __constant__ int SUBBASE[10] = {0, 8208, 16416, 32832, 49248,
                                           65664, 82080, 114912, 147744, 180576};
__device__ __constant__ int SUBW[10]    = {16, 16, 32, 32, 32, 32, 64, 64, 64, 64};

// -------- Kernel 1: fused pack+build, 4 chars per block --------
__global__ __launch_bounds__(512) void build_pe(
    const float* __restrict__ emb,
    const float* __restrict__ w2, const float* __restrict__ w3,
    const float* __restrict__ w4, const float* __restrict__ w5,
    const float* __restrict__ w6,
    __half* __restrict__ pe)
{
    __shared__ float e[4][EMB];
    const int tid = threadIdx.x;
    const int c0  = blockIdx.x * 4;
    {
        const int ch = tid >> 7, i = tid & 127;
        const int c  = c0 + ch;
        e[ch][i] = (c < VOC) ? emb[c * EMB + i] : 0.f;   // c>=VOC -> zero row
    }
    __syncthreads();

    const int col = tid;
    if (col >= NCOL) return;

    int k, jpad, base, seg; const float* w;
    if (col < 32)       { k = 2; jpad = 2; base = 0;   seg = 0; w = w2; }
    else if (col < 96)  { k = 3; jpad = 4; base = 32;  seg = 1; w = w3; }
    else if (col < 160) { k = 4; jpad = 4; base = 96;  seg = 2; w = w4; }
    else if (col < 288) { k = 5; jpad = 8; base = 160; seg = 3; w = w5; }
    else                { k = 6; jpad = 8; base = 288; seg = 4; w = w6; }

    const int r   = col - base;
    const int ol  = (jpad == 2) ? (r >> 1) : (jpad == 4) ? (r >> 2) : (r >> 3);
    const int j   = r & (jpad - 1);
    const int sub = seg * 2 + (ol >> 3);
    const int loc = (ol & 7) * jpad + j;

    float a0 = 0.f, a1 = 0.f, a2 = 0.f, a3 = 0.f;
    if (j < k) {                       // padded taps (j>=k) stay zero
        const float* wp = w + (ol * EMB) * k + j;
        #pragma unroll 8
        for (int i = 0; i < EMB; ++i) {
            const float wv = wp[i * k];      // w[(ol*EMB+i)*k + j]
            a0 += wv * e[0][i]; a1 += wv * e[1][i];
            a2 += wv * e[2][i]; a3 += wv * e[3][i];
        }
    }
    const int W = SUBW[sub], Bb = SUBBASE[sub];
    const float a[4] = {a0, a1, a2, a3};
    #pragma unroll
    for (int ch = 0; ch < 4; ++ch) {
        const int c = c0 + ch;
        if (c <= VOC) pe[Bb + c * W + loc] = __float2half(a[ch]);
    }
}

// -------- Kernel 2: LDS-resident half-table conv + max --------
__device__ __forceinline__ float2 h2tof2(int u) {
    return __half22float2(__builtin_bit_cast(__half2, u));
}

template<int K> struct LdT;
template<> struct LdT<2> { using T = int;  };
template<> struct LdT<3> { using T = int2; };
template<> struct LdT<4> { using T = int2; };
template<> struct LdT<5> { using T = int4; };
template<> struct LdT<6> { using T = int4; };

template<int K>
__device__ __forceinline__ void unpack(typename LdT<K>::T q, float* v) {
    if constexpr (K == 2) {
        float2 f = h2tof2(q); v[0] = f.x; v[1] = f.y;
    } else if constexpr (K == 3) {
        float2 f0 = h2tof2(q.x), f1 = h2tof2(q.y);
        v[0] = f0.x; v[1] = f0.y; v[2] = f1.x;
    } else if constexpr (K == 4) {
        float2 f0 = h2tof2(q.x), f1 = h2tof2(q.y);
        v[0] = f0.x; v[1] = f0.y; v[2] = f1.x; v[3] = f1.y;
    } else if constexpr (K == 5) {
        float2 f0 = h2tof2(q.x), f1 = h2tof2(q.y), f2 = h2tof2(q.z);
        v[0] = f0.x; v[1] = f0.y; v[2] = f1.x; v[3] = f1.y; v[4] = f2.x;
    } else {
        float2 f0 = h2tof2(q.x), f1 = h2tof2(q.y), f2 = h2tof2(q.z);
        v[0] = f0.x; v[1] = f0.y; v[2] = f1.x; v[3] = f1.y;
        v[4] = f2.x; v[5] = f2.y;
    }
}

// sc: row-major [word][SCP] u16 pre-multiplied (c*rowBytes)>>1.
// 4 x ds_read_b128 pulls all 32 tap offsets into registers up front;
// per-tap address = (extract u16 << 1) + lb  (register-only, no DS).
template<int K, int PAD, int LANEB>
__device__ __forceinline__ float convseg(
    const char* __restrict__ tb, const unsigned short* __restrict__ sc,
    int w, int lb, float bias)
{
    using LT = typename LdT<K>::T;
    constexpr int LOUT = L_SEQ + 2 * PAD - K + 1;

    int4 s4[4];
    {
        const int4* sp = (const int4*)(sc + w * SCP);   // 96B pitch, 16B aligned
        #pragma unroll
        for (int g = 0; g < 4; ++g) s4[g] = sp[g];
    }

    float s[LOUT];
    #pragma unroll
    for (int t = 0; t < LOUT; ++t) s[t] = bias;

    #pragma unroll
    for (int g = 0; g < 4; ++g) {
        const int dd[4] = {s4[g].x, s4[g].y, s4[g].z, s4[g].w};
        LT q[8];
        #pragma unroll
        for (int u = 0; u < 8; ++u) {
            const int pm = (u & 1) ? (int)(((unsigned)dd[u >> 1]) >> 16)
                                   : (dd[u >> 1] & 0xffff);
            q[u] = *(const LT*)(tb + (pm << 1) + lb);
        }
        #pragma unroll
        for (int u = 0; u < 8; ++u) {
            const int tp = g * 8 + u;
            float v[K];
            unpack<K>(q[u], v);
            #pragma unroll
            for (int j = 0; j < K; ++j) {
                const int t = tp + PAD - j;
                if (t >= 0 && t < LOUT) s[t] += v[j];
            }
        }
    }

    float m = s[0];
    #pragma unroll
    for (int t = 1; t < LOUT; ++t) m = fmaxf(m, s[t]);
    return m;
}

__global__ __launch_bounds__(512, 4) void conv_max(
    const int*    __restrict__ word,
    const __half* __restrict__ pe,
    const float* __restrict__ b2, const float* __restrict__ b3,
    const float* __restrict__ b4, const float* __restrict__ b5,
    const float* __restrict__ b6,
    float*       __restrict__ out)
{
    // 65,664 B half-table + 12,288 B sc = 77,952 B -> 2 blocks/CU (160 KiB)
    __shared__ __align__(16) __half tab[513 * 64];
    __shared__ __align__(16) unsigned short sc16[WPB * SCP];

    const int tid  = threadIdx.x;
    const int sub  = blockIdx.x % 10;     // block-uniform (seg, filter-half)
    const int wb   = blockIdx.x / 10;
    const int seg  = sub >> 1;
    const int half = sub & 1;

    // stage half-subtable: contiguous, coalesced, L2-resident
    const int  W16 = SUBW[sub];
    const int  nI4 = (513 * W16) >> 3;
    const int4* src = (const int4*)(pe + SUBBASE[sub]);
    int4* dst = (int4*)tab;
    for (int i = tid; i < nI4; i += 512) dst[i] = src[i];

    // stage pre-multiplied char offsets, row-major [word][SCP] u16
    const int shb = (seg == 0) ? 4 : (seg <= 2) ? 5 : 6;   // log2(rowB/2)
    #pragma unroll
    for (int r = 0; r < 8; ++r) {
        const int i  = tid + r * 512;                       // 0..4095
        const int c  = word[wb * (WPB * L_SEQ) + i];        // coalesced
        const int ce = (c >= 0) ? c : VOC;
        sc16[(i >> 5) * SCP + (i & 31)] = (unsigned short)(ce << shb);
    }
    __syncthreads();

    const int ol = tid & 7;               // filter within half
    const int w0 = tid >> 3;              // word 0..63; second word +64
    const float* bp = (seg == 0) ? b2 : (seg == 1) ? b3 :
                      (seg == 2) ? b4 : (seg == 3) ? b5 : b6;
    const float bias = bp[half * 8 + ol];
    const char* tb = (const char*)tab;

    float m0, m1;
    switch (seg) {
        case 0:  m0 = convseg<2, 0, 4 >(tb, sc16, w0,      ol * 4,  bias);
                 m1 = convseg<2, 0, 4 >(tb, sc16, w0 + 64, ol * 4,  bias); break;
        case 1:  m0 = convseg<3, 0, 8 >(tb, sc16, w0,      ol * 8,  bias);
                 m1 = convseg<3, 0, 8 >(tb, sc16, w0 + 64, ol * 8,  bias); break;
        case 2:  m0 = convseg<4, 1, 8 >(tb, sc16, w0,      ol * 8,  bias);
                 m1 = convseg<4, 1, 8 >(tb, sc16, w0 + 64, ol * 8,  bias); break;
        case 3:  m0 = convseg<5, 2, 16>(tb, sc16, w0,      ol * 16, bias);
                 m1 = convseg<5, 2, 16>(tb, sc16, w0 + 64, ol * 16, bias); break;
        default: m0 = convseg<6, 3, 16>(tb, sc16, w0,      ol * 16, bias);
                 m1 = convseg<6, 3, 16>(tb, sc16, w0 + 64, ol * 16, bias); break;
    }
    const int oc = seg * 16 + half * 8 + ol;
    out[(wb * WPB + w0     ) * 80 + oc] = m0;
    out[(wb * WPB + w0 + 64) * 80 + oc] = m1;
}

extern "C" void kernel_launch(void* const* d_in, const int* in_sizes, int n_in,
                              void* d_out, int out_size, void* d_ws, size_t ws_size,
                              hipStream_t stream)
{
    const int*   word = (const int*)  d_in[0];
    const float* emb  = (const float*)d_in[1];
    const float* w2   = (const float*)d_in[2];
    const float* b2   = (const float*)d_in[3];
    const float* w3   = (const float*)d_in[4];
    const float* b3   = (const float*)d_in[5];
    const float* w4   = (const float*)d_in[6];
    const float* b4   = (const float*)d_in[7];
    const float* w5   = (const float*)d_in[8];
    const float* b5   = (const float*)d_in[9];
    const float* w6   = (const float*)d_in[10];
    const float* b6   = (const float*)d_in[11];
    float* out = (float*)d_out;

    __half* pe16 = (__half*)d_ws;   // 426,816 B

    build_pe<<<129, 512, 0, stream>>>(emb, w2, w3, w4, w5, w6, pe16);

    conv_max<<<10 * (NWORDS / WPB), 512, 0, stream>>>(
        word, pe16, b2, b3, b4, b5, b6, out);
}